// Round 1
// baseline (761.562 us; speedup 1.0000x reference)
//
#include <hip/hip_runtime.h>
#include <math.h>

#define B_   16384
#define D_   1024
#define P_   1024
#define K3_  3072   // [hi | lo | hi] (A-side) x [hi | hi | lo] (B-side)
#define OUT_ 25

typedef unsigned short u16;
typedef unsigned int   u32;
typedef unsigned long long u64;
typedef __attribute__((ext_vector_type(8))) short short8;   // bf16x8 MFMA frag (4 VGPRs)
typedef __attribute__((ext_vector_type(4))) float f32x4;    // MFMA acc

struct alignas(8) U16x4 { u16 x, y, z, w; };

__device__ __forceinline__ u16 f2bf(float f) {
  u32 u = __float_as_uint(f);
  u32 r = (u + 0x7FFFu + ((u >> 16) & 1u)) >> 16;   // RNE
  return (u16)r;
}
__device__ __forceinline__ float bf2f(u16 h) {
  return __uint_as_float(((u32)h) << 16);
}
// monotonic fp32 -> u32 (handles negatives; no NaNs in this problem)
__device__ __forceinline__ u32 ordkey(float f) {
  u32 u = __float_as_uint(f);
  return (u & 0x80000000u) ? ~u : (u | 0x80000000u);
}
__device__ __forceinline__ void gload_lds16(const u16* g, u16* l) {
  __builtin_amdgcn_global_load_lds(
      (const __attribute__((address_space(1))) u32*)g,
      (__attribute__((address_space(3))) u32*)l, 16, 0, 0);
}

// ---------------- conversion kernels ----------------

// A-side split: out[r][0:1024]=hi, [1024:2048]=lo, [2048:3072]=hi
__global__ void convA(const float* __restrict__ in, u16* __restrict__ out) {
  int r = blockIdx.x, t = threadIdx.x;
  float4 x = ((const float4*)(in + (size_t)r * D_))[t];
  U16x4 h, l;
  h.x = f2bf(x.x); l.x = f2bf(x.x - bf2f(h.x));
  h.y = f2bf(x.y); l.y = f2bf(x.y - bf2f(h.y));
  h.z = f2bf(x.z); l.z = f2bf(x.z - bf2f(h.z));
  h.w = f2bf(x.w); l.w = f2bf(x.w - bf2f(h.w));
  u16* o = out + (size_t)r * K3_ + t * 4;
  *(U16x4*)(o)          = h;
  *(U16x4*)(o + D_)     = l;
  *(U16x4*)(o + 2 * D_) = h;
}

// B-side split: hi, hi, lo
__global__ void convB(const float* __restrict__ in, u16* __restrict__ out) {
  int r = blockIdx.x, t = threadIdx.x;
  float4 x = ((const float4*)(in + (size_t)r * D_))[t];
  U16x4 h, l;
  h.x = f2bf(x.x); l.x = f2bf(x.x - bf2f(h.x));
  h.y = f2bf(x.y); l.y = f2bf(x.y - bf2f(h.y));
  h.z = f2bf(x.z); l.z = f2bf(x.z - bf2f(h.z));
  h.w = f2bf(x.w); l.w = f2bf(x.w - bf2f(h.w));
  u16* o = out + (size_t)r * K3_ + t * 4;
  *(U16x4*)(o)          = h;
  *(U16x4*)(o + D_)     = h;
  *(U16x4*)(o + 2 * D_) = l;
}

// protos: emit A-side + B-side splits, plus p_sq, u = p.w1, v = p.w2
__global__ void convProtos(const float* __restrict__ protos, const float* __restrict__ lin_w,
                           u16* __restrict__ p3A, u16* __restrict__ p3B,
                           float* __restrict__ psq, float* __restrict__ uu, float* __restrict__ vv) {
  int r = blockIdx.x, t = threadIdx.x;
  float4 x  = ((const float4*)(protos + (size_t)r * D_))[t];
  float4 w1 = ((const float4*)(lin_w))[t];
  float4 w2 = ((const float4*)(lin_w + D_))[t];
  U16x4 h, l;
  h.x = f2bf(x.x); l.x = f2bf(x.x - bf2f(h.x));
  h.y = f2bf(x.y); l.y = f2bf(x.y - bf2f(h.y));
  h.z = f2bf(x.z); l.z = f2bf(x.z - bf2f(h.z));
  h.w = f2bf(x.w); l.w = f2bf(x.w - bf2f(h.w));
  u16* oa = p3A + (size_t)r * K3_ + t * 4;
  *(U16x4*)(oa) = h; *(U16x4*)(oa + D_) = l; *(U16x4*)(oa + 2 * D_) = h;
  u16* ob = p3B + (size_t)r * K3_ + t * 4;
  *(U16x4*)(ob) = h; *(U16x4*)(ob + D_) = h; *(U16x4*)(ob + 2 * D_) = l;

  float s1 = x.x*x.x + x.y*x.y + x.z*x.z + x.w*x.w;
  float s2 = x.x*w1.x + x.y*w1.y + x.z*w1.z + x.w*w1.w;
  float s3 = x.x*w2.x + x.y*w2.y + x.z*w2.z + x.w*w2.w;
  #pragma unroll
  for (int mk = 1; mk < 64; mk <<= 1) {
    s1 += __shfl_xor(s1, mk);
    s2 += __shfl_xor(s2, mk);
    s3 += __shfl_xor(s3, mk);
  }
  __shared__ float r1[4], r2[4], r3[4];
  if ((t & 63) == 0) { int w = t >> 6; r1[w] = s1; r2[w] = s2; r3[w] = s3; }
  __syncthreads();
  if (t == 0) {
    psq[r] = r1[0] + r1[1] + r1[2] + r1[3];
    uu[r]  = r2[0] + r2[1] + r2[2] + r2[3];
    vv[r]  = r3[0] + r3[1] + r3[2] + r3[3];
  }
}

// transpose W [D][D] and emit B-side split of Wt (Wt[j][k] = W[k][j])
__global__ void convWt(const float* __restrict__ W, u16* __restrict__ wt3B) {
  __shared__ float tile[64][65];
  int bx = blockIdx.x;  // source row block (k)
  int by = blockIdx.y;  // source col block (j)
  int t = threadIdx.x;
  int c4 = (t & 15) * 4, r0 = t >> 4;
  #pragma unroll
  for (int rr = 0; rr < 64; rr += 16) {
    int r = rr + r0;
    float4 x = *(const float4*)(W + (size_t)(bx * 64 + r) * D_ + by * 64 + c4);
    tile[r][c4 + 0] = x.x; tile[r][c4 + 1] = x.y; tile[r][c4 + 2] = x.z; tile[r][c4 + 3] = x.w;
  }
  __syncthreads();
  #pragma unroll
  for (int rr = 0; rr < 64; rr += 16) {
    int r = rr + r0;                 // j-local
    U16x4 h, l;
    float v0 = tile[c4 + 0][r], v1 = tile[c4 + 1][r], v2 = tile[c4 + 2][r], v3 = tile[c4 + 3][r];
    h.x = f2bf(v0); l.x = f2bf(v0 - bf2f(h.x));
    h.y = f2bf(v1); l.y = f2bf(v1 - bf2f(h.y));
    h.z = f2bf(v2); l.z = f2bf(v2 - bf2f(h.z));
    h.w = f2bf(v3); l.w = f2bf(v3 - bf2f(h.w));
    u16* o = wt3B + (size_t)(by * 64 + r) * K3_ + bx * 64 + c4;
    *(U16x4*)(o) = h; *(U16x4*)(o + D_) = h; *(U16x4*)(o + 2 * D_) = l;
  }
}

// ---------------- split-bf16 BT GEMM (m97 structure) ----------------
// C[M,N] = A3[M,3072] . B3[N,3072]^T  (== fp32-accurate A.B^T over K=1024)
// MODE 0: store C. MODE 1: d2 = psq[n]-2*c, fused row-argmin via packed atomicMin.
// MODE 2: store leaky_relu(c + bias[n], 0.01).
template<int MODE>
__global__ __launch_bounds__(256) void gemm_bt(
    const u16* __restrict__ A, const u16* __restrict__ B, int NTN,
    float* __restrict__ C, int ldc,
    const float* __restrict__ psq, u64* __restrict__ packed,
    const float* __restrict__ bias)
{
  __shared__ u16 As[128 * 32];
  __shared__ u16 Bs[128 * 32];

  int bid = blockIdx.x;
  int nwg = gridDim.x;
  int q = nwg >> 3;                       // nwg % 8 == 0 in all uses
  int wg = (bid & 7) * q + (bid >> 3);    // XCD-aware swizzle
  int tm = wg / NTN, tn = wg % NTN;
  int m0 = tm * 128, n0 = tn * 128;

  int t = threadIdx.x;
  int w = t >> 6, lane = t & 63;
  int wr = w >> 1, wc = w & 1;            // 2x2 waves of 64x64
  int lr = lane & 15, lg = lane >> 4;

  // staging: wave 0/1 -> As halves, wave 2/3 -> Bs halves; 4 issues x 1KB per wave
  const u16* src = (w < 2) ? A : B;
  int base_row = (w < 2) ? m0 : n0;
  int half = w & 1;
  int srow = base_row + half * 64 + (lane >> 2);   // +16 per issue
  int scol = (lane & 3) * 8;
  const u16* gsrc = src + (size_t)srow * K3_ + scol;
  u16* lbase = ((w < 2) ? As : Bs) + half * 2048;  // lane*16B added by HW

  f32x4 acc[4][4];
  #pragma unroll
  for (int i = 0; i < 4; ++i)
    #pragma unroll
    for (int j = 0; j < 4; ++j)
      acc[i][j] = (f32x4){0.f, 0.f, 0.f, 0.f};

  for (int kt = 0; kt < K3_ / 32; ++kt) {
    #pragma unroll
    for (int p = 0; p < 4; ++p)
      gload_lds16(gsrc + kt * 32 + (size_t)p * 16 * K3_, lbase + p * 512);
    __syncthreads();

    short8 af[4], bfr[4];
    #pragma unroll
    for (int i = 0; i < 4; ++i)
      af[i] = *(const short8*)&As[(wr * 64 + i * 16 + lr) * 32 + lg * 8];
    #pragma unroll
    for (int j = 0; j < 4; ++j)
      bfr[j] = *(const short8*)&Bs[(wc * 64 + j * 16 + lr) * 32 + lg * 8];
    #pragma unroll
    for (int i = 0; i < 4; ++i)
      #pragma unroll
      for (int j = 0; j < 4; ++j)
        acc[i][j] = __builtin_amdgcn_mfma_f32_16x16x32_bf16(af[i], bfr[j], acc[i][j], 0, 0, 0);
    __syncthreads();
  }

  if (MODE == 1) {
    float pq[4];
    #pragma unroll
    for (int j = 0; j < 4; ++j) pq[j] = psq[n0 + wc * 64 + j * 16 + lr];
    #pragma unroll
    for (int i = 0; i < 4; ++i) {
      #pragma unroll
      for (int r = 0; r < 4; ++r) {
        float best = 1e30f; int bestn = 0x7fffffff;
        #pragma unroll
        for (int j = 0; j < 4; ++j) {
          int n = n0 + wc * 64 + j * 16 + lr;
          float d = pq[j] - 2.0f * acc[i][j][r];
          if (d < best || (d == best && n < bestn)) { best = d; bestn = n; }
        }
        #pragma unroll
        for (int mk = 1; mk < 16; mk <<= 1) {
          float od = __shfl_xor(best, mk);
          int   on = __shfl_xor(bestn, mk);
          if (od < best || (od == best && on < bestn)) { best = od; bestn = on; }
        }
        if (lr == 0) {
          int m = m0 + wr * 64 + i * 16 + lg * 4 + r;
          u64 key = ((u64)ordkey(best) << 32) | (u32)bestn;
          atomicMin(&packed[m], key);
        }
      }
    }
  } else {
    float bc[4];
    if (MODE == 2) {
      #pragma unroll
      for (int j = 0; j < 4; ++j) bc[j] = bias[n0 + wc * 64 + j * 16 + lr];
    }
    #pragma unroll
    for (int i = 0; i < 4; ++i)
      #pragma unroll
      for (int j = 0; j < 4; ++j)
        #pragma unroll
        for (int r = 0; r < 4; ++r) {
          int m = m0 + wr * 64 + i * 16 + lg * 4 + r;
          int n = n0 + wc * 64 + j * 16 + lr;
          float val = acc[i][j][r];
          if (MODE == 2) { val += bc[j]; val = val >= 0.f ? val : 0.01f * val; }
          C[(size_t)m * ldc + n] = val;
        }
  }
}

// ---------------- mix kernel: lam + adaptive mixup, writes A-side split ----------------
__global__ void mix_kernel(const u64* __restrict__ packed, const int* __restrict__ index,
                           const float* __restrict__ Tm, const float* __restrict__ protos,
                           const float* __restrict__ patient,
                           const float* __restrict__ uu, const float* __restrict__ vv,
                           const float* __restrict__ bilb, u16* __restrict__ mixed3)
{
  int b = blockIdx.x, t = threadIdx.x;
  int la = (int)(packed[b] & 0xffffffffULL);
  int ib = index[b];
  int lb = (int)(packed[ib] & 0xffffffffULL);

  float4 ta = ((const float4*)(Tm     + (size_t)la * D_))[t];
  float4 pb = ((const float4*)(protos + (size_t)lb * D_))[t];
  float part = ta.x*pb.x + ta.y*pb.y + ta.z*pb.z + ta.w*pb.w;
  #pragma unroll
  for (int mk = 1; mk < 64; mk <<= 1) part += __shfl_xor(part, mk);
  __shared__ float ws4[4];
  __shared__ float lamsh;
  if ((t & 63) == 0) ws4[t >> 6] = part;
  __syncthreads();
  if (t == 0) {
    float dot = ws4[0] + ws4[1] + ws4[2] + ws4[3];
    float z = dot + bilb[0] + uu[la] + vv[lb];
    lamsh = 1.0f / (1.0f + expf(-z));
  }
  __syncthreads();
  float lam = lamsh, oml = 1.0f - lam;

  float4 xa = ((const float4*)(patient + (size_t)b  * D_))[t];
  float4 xb = ((const float4*)(patient + (size_t)ib * D_))[t];
  float m0v = lam * xa.x + oml * xb.x;
  float m1v = lam * xa.y + oml * xb.y;
  float m2v = lam * xa.z + oml * xb.z;
  float m3v = lam * xa.w + oml * xb.w;
  U16x4 h, l;
  h.x = f2bf(m0v); l.x = f2bf(m0v - bf2f(h.x));
  h.y = f2bf(m1v); l.y = f2bf(m1v - bf2f(h.y));
  h.z = f2bf(m2v); l.z = f2bf(m2v - bf2f(h.z));
  h.w = f2bf(m3v); l.w = f2bf(m3v - bf2f(h.w));
  u16* o = mixed3 + (size_t)b * K3_ + t * 4;
  *(U16x4*)(o) = h; *(U16x4*)(o + D_) = l; *(U16x4*)(o + 2 * D_) = h;
}

// ---------------- final tiny GEMM: out = leaky_pl @ cls_w^T + cls_b ----------------
__global__ __launch_bounds__(256) void cls_kernel(const float* __restrict__ pl,
                                                  const float* __restrict__ w,
                                                  const float* __restrict__ bias,
                                                  float* __restrict__ out)
{
  int r0 = blockIdx.x * 16;
  int t = threadIdx.x;
  for (int task = t; task < 16 * OUT_; task += 256) {
    int rr = task / OUT_, o = task - rr * OUT_;
    const float4* prow = (const float4*)(pl + (size_t)(r0 + rr) * P_);
    const float4* wrow = (const float4*)(w  + (size_t)o * P_);
    float acc = 0.f;
    #pragma unroll 4
    for (int k = 0; k < P_ / 4; ++k) {
      float4 a = prow[k], c = wrow[k];
      acc = fmaf(a.x, c.x, acc); acc = fmaf(a.y, c.y, acc);
      acc = fmaf(a.z, c.z, acc); acc = fmaf(a.w, c.w, acc);
    }
    out[(size_t)(r0 + rr) * OUT_ + o] = acc + bias[o];
  }
}

extern "C" void kernel_launch(void* const* d_in, const int* in_sizes, int n_in,
                              void* d_out, int out_size, void* d_ws, size_t ws_size,
                              hipStream_t stream)
{
  const float* patient = (const float*)d_in[0];
  const float* protos  = (const float*)d_in[1];
  const int*   index   = (const int*)d_in[2];
  const float* W       = (const float*)d_in[3];
  const float* bilb    = (const float*)d_in[4];
  const float* lin_w   = (const float*)d_in[5];
  const float* pfc_w   = (const float*)d_in[6];
  const float* pfc_b   = (const float*)d_in[7];
  const float* cls_w   = (const float*)d_in[8];
  const float* cls_b   = (const float*)d_in[9];
  float* out = (float*)d_out;

  char* ws = (char*)d_ws;
  size_t off = 0;
  auto carve = [&](size_t bytes) -> char* {
    char* p = ws + off; off += (bytes + 255) & ~(size_t)255; return p;
  };
  u16* buf3   = (u16*)carve((size_t)B_ * K3_ * 2);   // patient3A, later mixed3
  float* pl   = (float*)carve((size_t)B_ * P_ * 4);
  u16* p3A    = (u16*)carve((size_t)P_ * K3_ * 2);
  u16* p3B    = (u16*)carve((size_t)P_ * K3_ * 2);
  u16* pfc3B  = (u16*)carve((size_t)P_ * K3_ * 2);
  u16* wt3B   = (u16*)carve((size_t)D_ * K3_ * 2);
  float* Tm   = (float*)carve((size_t)P_ * D_ * 4);
  u64* packed = (u64*)carve((size_t)B_ * 8);
  float* psq  = (float*)carve(P_ * 4);
  float* uu   = (float*)carve(P_ * 4);
  float* vv   = (float*)carve(P_ * 4);

  // init argmin keys to +inf
  hipMemsetAsync(packed, 0xFF, (size_t)B_ * 8, stream);

  convProtos<<<P_, 256, 0, stream>>>(protos, lin_w, p3A, p3B, psq, uu, vv);
  convWt<<<dim3(16, 16), 256, 0, stream>>>(W, wt3B);
  convB<<<P_, 256, 0, stream>>>(pfc_w, pfc3B);
  convA<<<B_, 256, 0, stream>>>(patient, buf3);

  // T = protos @ W   (via protos3A . Wt3B^T)
  gemm_bt<0><<<64, 256, 0, stream>>>(p3A, wt3B, 8, Tm, D_, nullptr, nullptr, nullptr);
  // distances + fused argmin
  gemm_bt<1><<<1024, 256, 0, stream>>>(buf3, p3B, 8, nullptr, 0, psq, packed, nullptr);
  // lam + mixup (overwrites buf3 with mixed3)
  mix_kernel<<<B_, 256, 0, stream>>>(packed, index, Tm, protos, patient, uu, vv, bilb, buf3);
  // proto_logits with fused bias+leaky
  gemm_bt<2><<<1024, 256, 0, stream>>>(buf3, pfc3B, 8, pl, P_, nullptr, nullptr, pfc_b);
  // final 25-wide projection
  cls_kernel<<<B_ / 16, 256, 0, stream>>>(pl, cls_w, cls_b, out);
}

// Round 2
// 550.567 us; speedup vs baseline: 1.3832x; 1.3832x over previous
//
#include <hip/hip_runtime.h>
#include <math.h>

#define B_   16384
#define D_   1024
#define P_   1024
#define KS_  2048   // storage: [hi | lo]; logical K = 3 phases x 1024
#define OUT_ 25

typedef unsigned short u16;
typedef unsigned int   u32;
typedef unsigned long long u64;
typedef __attribute__((ext_vector_type(8))) short short8;   // bf16x8 MFMA frag
typedef __attribute__((ext_vector_type(4))) float f32x4;    // MFMA acc
typedef _Float16 half_t;
typedef __attribute__((ext_vector_type(2))) _Float16 h2;

struct alignas(8) U16x4 { u16 x, y, z, w; };
struct alignas(8) H4 { half_t x, y, z, w; };
struct alignas(16) H8 { h2 a, b, c, d; };

#if defined(__has_builtin)
#if __has_builtin(__builtin_amdgcn_fdot2)
#define HAS_FDOT2 1
#endif
#endif

__device__ __forceinline__ u16 f2bf(float f) {
  u32 u = __float_as_uint(f);
  u32 r = (u + 0x7FFFu + ((u >> 16) & 1u)) >> 16;   // RNE
  return (u16)r;
}
__device__ __forceinline__ float bf2f(u16 h) {
  return __uint_as_float(((u32)h) << 16);
}
// monotonic fp32 -> u32 (no NaNs in this problem)
__device__ __forceinline__ u32 ordkey(float f) {
  u32 u = __float_as_uint(f);
  return (u & 0x80000000u) ? ~u : (u | 0x80000000u);
}
__device__ __forceinline__ void gload_lds16(const u16* g, u16* l) {
  __builtin_amdgcn_global_load_lds(
      (const __attribute__((address_space(1))) u32*)g,
      (__attribute__((address_space(3))) u32*)l, 16, 0, 0);
}
__device__ __forceinline__ float dot8(const H8& a, const H8& b, float c) {
#ifdef HAS_FDOT2
  c = __builtin_amdgcn_fdot2(a.a, b.a, c, false);
  c = __builtin_amdgcn_fdot2(a.b, b.b, c, false);
  c = __builtin_amdgcn_fdot2(a.c, b.c, c, false);
  c = __builtin_amdgcn_fdot2(a.d, b.d, c, false);
#else
  c += (float)a.a.x * (float)b.a.x + (float)a.a.y * (float)b.a.y;
  c += (float)a.b.x * (float)b.b.x + (float)a.b.y * (float)b.b.y;
  c += (float)a.c.x * (float)b.c.x + (float)a.c.y * (float)b.c.y;
  c += (float)a.d.x * (float)b.d.x + (float)a.d.y * (float)b.d.y;
#endif
  return c;
}

// ---------------- conversion kernels ----------------

// split: out[r][0:1024]=hi(bf16), [1024:2048]=lo(bf16 of residual)
__global__ void conv_split(const float* __restrict__ in, u16* __restrict__ out) {
  int r = blockIdx.x, t = threadIdx.x;
  float4 x = ((const float4*)(in + (size_t)r * D_))[t];
  U16x4 h, l;
  h.x = f2bf(x.x); l.x = f2bf(x.x - bf2f(h.x));
  h.y = f2bf(x.y); l.y = f2bf(x.y - bf2f(h.y));
  h.z = f2bf(x.z); l.z = f2bf(x.z - bf2f(h.z));
  h.w = f2bf(x.w); l.w = f2bf(x.w - bf2f(h.w));
  u16* o = out + (size_t)r * KS_ + t * 4;
  *(U16x4*)(o)      = h;
  *(U16x4*)(o + D_) = l;
}

// protos: split + p_sq + u = p.w1 + v = p.w2
__global__ void convProtos(const float* __restrict__ protos, const float* __restrict__ lin_w,
                           u16* __restrict__ p2,
                           float* __restrict__ psq, float* __restrict__ uu, float* __restrict__ vv) {
  int r = blockIdx.x, t = threadIdx.x;
  float4 x  = ((const float4*)(protos + (size_t)r * D_))[t];
  float4 w1 = ((const float4*)(lin_w))[t];
  float4 w2 = ((const float4*)(lin_w + D_))[t];
  U16x4 h, l;
  h.x = f2bf(x.x); l.x = f2bf(x.x - bf2f(h.x));
  h.y = f2bf(x.y); l.y = f2bf(x.y - bf2f(h.y));
  h.z = f2bf(x.z); l.z = f2bf(x.z - bf2f(h.z));
  h.w = f2bf(x.w); l.w = f2bf(x.w - bf2f(h.w));
  u16* o = p2 + (size_t)r * KS_ + t * 4;
  *(U16x4*)(o) = h; *(U16x4*)(o + D_) = l;

  float s1 = x.x*x.x + x.y*x.y + x.z*x.z + x.w*x.w;
  float s2 = x.x*w1.x + x.y*w1.y + x.z*w1.z + x.w*w1.w;
  float s3 = x.x*w2.x + x.y*w2.y + x.z*w2.z + x.w*w2.w;
  #pragma unroll
  for (int mk = 1; mk < 64; mk <<= 1) {
    s1 += __shfl_xor(s1, mk);
    s2 += __shfl_xor(s2, mk);
    s3 += __shfl_xor(s3, mk);
  }
  __shared__ float r1[4], r2[4], r3[4];
  if ((t & 63) == 0) { int w = t >> 6; r1[w] = s1; r2[w] = s2; r3[w] = s3; }
  __syncthreads();
  if (t == 0) {
    psq[r] = r1[0] + r1[1] + r1[2] + r1[3];
    uu[r]  = r2[0] + r2[1] + r2[2] + r2[3];
    vv[r]  = r3[0] + r3[1] + r3[2] + r3[3];
  }
}

// transpose W [D][D], emit split of Wt (Wt[j][k] = W[k][j])
__global__ void convWt(const float* __restrict__ W, u16* __restrict__ wt2) {
  __shared__ float tile[64][65];
  int bx = blockIdx.x, by = blockIdx.y;
  int t = threadIdx.x;
  int c4 = (t & 15) * 4, r0 = t >> 4;
  #pragma unroll
  for (int rr = 0; rr < 64; rr += 16) {
    int r = rr + r0;
    float4 x = *(const float4*)(W + (size_t)(bx * 64 + r) * D_ + by * 64 + c4);
    tile[r][c4 + 0] = x.x; tile[r][c4 + 1] = x.y; tile[r][c4 + 2] = x.z; tile[r][c4 + 3] = x.w;
  }
  __syncthreads();
  #pragma unroll
  for (int rr = 0; rr < 64; rr += 16) {
    int r = rr + r0;
    U16x4 h, l;
    float v0 = tile[c4 + 0][r], v1 = tile[c4 + 1][r], v2 = tile[c4 + 2][r], v3 = tile[c4 + 3][r];
    h.x = f2bf(v0); l.x = f2bf(v0 - bf2f(h.x));
    h.y = f2bf(v1); l.y = f2bf(v1 - bf2f(h.y));
    h.z = f2bf(v2); l.z = f2bf(v2 - bf2f(h.z));
    h.w = f2bf(v3); l.w = f2bf(v3 - bf2f(h.w));
    u16* o = wt2 + (size_t)(by * 64 + r) * KS_ + bx * 64 + c4;
    *(U16x4*)(o) = h; *(U16x4*)(o + D_) = l;
  }
}

// ---------------- split-bf16 BT GEMM (m97 structure, 3 logical K-phases) ----------------
// C = A.B^T over K=1024 fp32-accurate via phases: ah.bh + al.bh + ah.bl
// A col base per phase {0,1024,0}; B col base per phase {0,0,1024}.
// MODE 0: store fp32 C. MODE 1: fused argmin of psq[n]-2*c via packed atomicMin.
// MODE 2: store fp16 leaky_relu(c + bias[n]).
template<int MODE>
__global__ __launch_bounds__(256) void gemm_bt(
    const u16* __restrict__ A, const u16* __restrict__ B, int NTN,
    float* __restrict__ C, u16* __restrict__ Ch, int ldc,
    const float* __restrict__ psq, u64* __restrict__ packed,
    const float* __restrict__ bias)
{
  __shared__ u16 As[128 * 32];
  __shared__ u16 Bs[128 * 32];

  int bid = blockIdx.x;
  int nwg = gridDim.x;
  int q = nwg >> 3;                       // nwg % 8 == 0 in all uses
  int wg = (bid & 7) * q + (bid >> 3);    // XCD-aware swizzle
  int tm = wg / NTN, tn = wg % NTN;
  int m0 = tm * 128, n0 = tn * 128;

  int t = threadIdx.x;
  int w = t >> 6, lane = t & 63;
  int wr = w >> 1, wc = w & 1;            // 2x2 waves of 64x64
  int lr = lane & 15, lg = lane >> 4;

  const u16* src = (w < 2) ? A : B;
  int base_row = (w < 2) ? m0 : n0;
  int half = w & 1;
  int srow = base_row + half * 64 + (lane >> 2);
  int scol = (lane & 3) * 8;
  const u16* gsrc = src + (size_t)srow * KS_ + scol;
  u16* lbase = ((w < 2) ? As : Bs) + half * 2048;

  f32x4 acc[4][4];
  #pragma unroll
  for (int i = 0; i < 4; ++i)
    #pragma unroll
    for (int j = 0; j < 4; ++j)
      acc[i][j] = (f32x4){0.f, 0.f, 0.f, 0.f};

  for (int kt = 0; kt < 96; ++kt) {
    int ph = kt >> 5, kk = kt & 31;
    int abase = (ph == 1) ? 1024 : 0;     // A phases: hi, lo, hi
    int bbase = (ph == 2) ? 1024 : 0;     // B phases: hi, hi, lo
    int kb = ((w < 2) ? abase : bbase) + kk * 32;
    #pragma unroll
    for (int p = 0; p < 4; ++p)
      gload_lds16(gsrc + kb + (size_t)p * 16 * KS_, lbase + p * 512);
    __syncthreads();

    short8 af[4], bfr[4];
    #pragma unroll
    for (int i = 0; i < 4; ++i)
      af[i] = *(const short8*)&As[(wr * 64 + i * 16 + lr) * 32 + lg * 8];
    #pragma unroll
    for (int j = 0; j < 4; ++j)
      bfr[j] = *(const short8*)&Bs[(wc * 64 + j * 16 + lr) * 32 + lg * 8];
    #pragma unroll
    for (int i = 0; i < 4; ++i)
      #pragma unroll
      for (int j = 0; j < 4; ++j)
        acc[i][j] = __builtin_amdgcn_mfma_f32_16x16x32_bf16(af[i], bfr[j], acc[i][j], 0, 0, 0);
    __syncthreads();
  }

  if (MODE == 1) {
    float pq[4];
    #pragma unroll
    for (int j = 0; j < 4; ++j) pq[j] = psq[n0 + wc * 64 + j * 16 + lr];
    #pragma unroll
    for (int i = 0; i < 4; ++i) {
      #pragma unroll
      for (int r = 0; r < 4; ++r) {
        float best = 1e30f; int bestn = 0x7fffffff;
        #pragma unroll
        for (int j = 0; j < 4; ++j) {
          int n = n0 + wc * 64 + j * 16 + lr;
          float d = pq[j] - 2.0f * acc[i][j][r];
          if (d < best || (d == best && n < bestn)) { best = d; bestn = n; }
        }
        #pragma unroll
        for (int mk = 1; mk < 16; mk <<= 1) {
          float od = __shfl_xor(best, mk);
          int   on = __shfl_xor(bestn, mk);
          if (od < best || (od == best && on < bestn)) { best = od; bestn = on; }
        }
        if (lr == 0) {
          int m = m0 + wr * 64 + i * 16 + lg * 4 + r;
          u64 key = ((u64)ordkey(best) << 32) | (u32)bestn;
          atomicMin(&packed[m], key);
        }
      }
    }
  } else {
    float bc[4];
    if (MODE == 2) {
      #pragma unroll
      for (int j = 0; j < 4; ++j) bc[j] = bias[n0 + wc * 64 + j * 16 + lr];
    }
    #pragma unroll
    for (int i = 0; i < 4; ++i)
      #pragma unroll
      for (int j = 0; j < 4; ++j)
        #pragma unroll
        for (int r = 0; r < 4; ++r) {
          int m = m0 + wr * 64 + i * 16 + lg * 4 + r;
          int n = n0 + wc * 64 + j * 16 + lr;
          float val = acc[i][j][r];
          if (MODE == 2) {
            val += bc[j]; val = val >= 0.f ? val : 0.01f * val;
            half_t hv = (half_t)val;
            Ch[(size_t)m * ldc + n] = __builtin_bit_cast(u16, hv);
          } else {
            C[(size_t)m * ldc + n] = val;
          }
        }
  }
}

// ---------------- mix kernel: lam + adaptive mixup, writes split ----------------
__global__ void mix_kernel(const u64* __restrict__ packed, const int* __restrict__ index,
                           const float* __restrict__ Tm, const float* __restrict__ protos,
                           const float* __restrict__ patient,
                           const float* __restrict__ uu, const float* __restrict__ vv,
                           const float* __restrict__ bilb, u16* __restrict__ mixed2)
{
  int b = blockIdx.x, t = threadIdx.x;
  int la = (int)(packed[b] & 0xffffffffULL);
  int ib = index[b];
  int lb = (int)(packed[ib] & 0xffffffffULL);

  float4 ta = ((const float4*)(Tm     + (size_t)la * D_))[t];
  float4 pb = ((const float4*)(protos + (size_t)lb * D_))[t];
  float part = ta.x*pb.x + ta.y*pb.y + ta.z*pb.z + ta.w*pb.w;
  #pragma unroll
  for (int mk = 1; mk < 64; mk <<= 1) part += __shfl_xor(part, mk);
  __shared__ float ws4[4];
  __shared__ float lamsh;
  if ((t & 63) == 0) ws4[t >> 6] = part;
  __syncthreads();
  if (t == 0) {
    float dot = ws4[0] + ws4[1] + ws4[2] + ws4[3];
    float z = dot + bilb[0] + uu[la] + vv[lb];
    lamsh = 1.0f / (1.0f + expf(-z));
  }
  __syncthreads();
  float lam = lamsh, oml = 1.0f - lam;

  float4 xa = ((const float4*)(patient + (size_t)b  * D_))[t];
  float4 xb = ((const float4*)(patient + (size_t)ib * D_))[t];
  float m0v = lam * xa.x + oml * xb.x;
  float m1v = lam * xa.y + oml * xb.y;
  float m2v = lam * xa.z + oml * xb.z;
  float m3v = lam * xa.w + oml * xb.w;
  U16x4 h, l;
  h.x = f2bf(m0v); l.x = f2bf(m0v - bf2f(h.x));
  h.y = f2bf(m1v); l.y = f2bf(m1v - bf2f(h.y));
  h.z = f2bf(m2v); l.z = f2bf(m2v - bf2f(h.z));
  h.w = f2bf(m3v); l.w = f2bf(m3v - bf2f(h.w));
  u16* o = mixed2 + (size_t)b * KS_ + t * 4;
  *(U16x4*)(o) = h; *(U16x4*)(o + D_) = l;
}

// ---------------- cls: out = pl_fp16 @ cls_w^T + b, w staged fp16 in LDS ----------------
// 256 blocks x 256 threads; 4 threads/row, 64 rows/block; fdot2 inner loop.
__global__ __launch_bounds__(256) void cls_kernel(const u16* __restrict__ pl,
                                                  const float* __restrict__ w,
                                                  const float* __restrict__ bias,
                                                  float* __restrict__ out)
{
  __shared__ half_t wl[25 * 1032];   // +8 half pad/row -> banks spread
  int t = threadIdx.x;
  for (int i = t; i < 25 * 256; i += 256) {   // 6400 float4 of cls_w
    float4 v = ((const float4*)w)[i];
    int o = i >> 8;             // i / 256
    int col = (i & 255) * 4;
    H4 hh; hh.x = (half_t)v.x; hh.y = (half_t)v.y; hh.z = (half_t)v.z; hh.w = (half_t)v.w;
    *(H4*)&wl[o * 1032 + col] = hh;
  }
  __syncthreads();

  int row = blockIdx.x * 64 + (t >> 2);
  int osub = t & 3;
  const H8* prow = (const H8*)(pl + (size_t)row * P_);
  float acc[7] = {0.f, 0.f, 0.f, 0.f, 0.f, 0.f, 0.f};

  for (int kk = 0; kk < 128; ++kk) {
    H8 a = prow[kk];
    #pragma unroll
    for (int j = 0; j < 7; ++j) {
      int o = 4 * j + osub;
      if (o < 25) {
        H8 wv = *(const H8*)&wl[o * 1032 + kk * 8];
        acc[j] = dot8(a, wv, acc[j]);
      }
    }
  }
  #pragma unroll
  for (int j = 0; j < 7; ++j) {
    int o = 4 * j + osub;
    if (o < 25) out[(size_t)row * OUT_ + o] = acc[j] + bias[o];
  }
}

extern "C" void kernel_launch(void* const* d_in, const int* in_sizes, int n_in,
                              void* d_out, int out_size, void* d_ws, size_t ws_size,
                              hipStream_t stream)
{
  const float* patient = (const float*)d_in[0];
  const float* protos  = (const float*)d_in[1];
  const int*   index   = (const int*)d_in[2];
  const float* W       = (const float*)d_in[3];
  const float* bilb    = (const float*)d_in[4];
  const float* lin_w   = (const float*)d_in[5];
  const float* pfc_w   = (const float*)d_in[6];
  const float* pfc_b   = (const float*)d_in[7];
  const float* cls_w   = (const float*)d_in[8];
  const float* cls_b   = (const float*)d_in[9];
  float* out = (float*)d_out;

  char* ws = (char*)d_ws;
  size_t off = 0;
  auto carve = [&](size_t bytes) -> char* {
    char* p = ws + off; off += (bytes + 255) & ~(size_t)255; return p;
  };
  u16* buf2   = (u16*)carve((size_t)B_ * KS_ * 2);   // patient split, later mixed split
  u16* plh    = (u16*)carve((size_t)B_ * P_ * 2);    // fp16 leaky(proto_logits)
  u16* p2     = (u16*)carve((size_t)P_ * KS_ * 2);   // protos split (A-side AND B-side)
  u16* pfc2   = (u16*)carve((size_t)P_ * KS_ * 2);
  u16* wt2    = (u16*)carve((size_t)D_ * KS_ * 2);
  float* Tm   = (float*)carve((size_t)P_ * D_ * 4);
  u64* packed = (u64*)carve((size_t)B_ * 8);
  float* psq  = (float*)carve(P_ * 4);
  float* uu   = (float*)carve(P_ * 4);
  float* vv   = (float*)carve(P_ * 4);

  hipMemsetAsync(packed, 0xFF, (size_t)B_ * 8, stream);

  convProtos<<<P_, 256, 0, stream>>>(protos, lin_w, p2, psq, uu, vv);
  convWt<<<dim3(16, 16), 256, 0, stream>>>(W, wt2);
  conv_split<<<P_, 256, 0, stream>>>(pfc_w, pfc2);
  conv_split<<<B_, 256, 0, stream>>>(patient, buf2);

  // T = protos @ W
  gemm_bt<0><<<64, 256, 0, stream>>>(p2, wt2, 8, Tm, nullptr, D_, nullptr, nullptr, nullptr);
  // distances + fused argmin
  gemm_bt<1><<<1024, 256, 0, stream>>>(buf2, p2, 8, nullptr, nullptr, 0, psq, packed, nullptr);
  // lam + mixup (overwrites buf2 with mixed split)
  mix_kernel<<<B_, 256, 0, stream>>>(packed, index, Tm, protos, patient, uu, vv, bilb, buf2);
  // proto_logits with fused bias+leaky -> fp16
  gemm_bt<2><<<1024, 256, 0, stream>>>(buf2, pfc2, 8, nullptr, plh, P_, nullptr, nullptr, pfc_b);
  // final 25-wide projection
  cls_kernel<<<256, 256, 0, stream>>>(plh, cls_w, cls_b, out);
}

// Round 3
// 431.694 us; speedup vs baseline: 1.7641x; 1.2754x over previous
//
#include <hip/hip_runtime.h>
#include <math.h>

#define B_   16384
#define D_   1024
#define P_   1024
#define KS_  2048   // storage: [hi | lo]; logical K = 3 phases x 1024
#define OUT_ 25
#define NT_  48     // 256-tile GEMM: 48 K-tiles of 64 (3 phases x 16)

typedef unsigned short u16;
typedef unsigned int   u32;
typedef unsigned long long u64;
typedef __attribute__((ext_vector_type(8))) short short8;   // bf16x8 MFMA frag
typedef __attribute__((ext_vector_type(4))) float f32x4;    // MFMA acc
typedef _Float16 half_t;
typedef __attribute__((ext_vector_type(2))) _Float16 h2;

struct alignas(8) U16x4 { u16 x, y, z, w; };
struct alignas(8) H4 { half_t x, y, z, w; };
struct alignas(16) H8 { h2 a, b, c, d; };

#if defined(__has_builtin)
#if __has_builtin(__builtin_amdgcn_fdot2)
#define HAS_FDOT2 1
#endif
#endif

#define SBAR()  __builtin_amdgcn_s_barrier()
#define SFENCE() __builtin_amdgcn_sched_barrier(0)
#define WAITV8() asm volatile("s_waitcnt vmcnt(8)" ::: "memory")
#define WAITV0() asm volatile("s_waitcnt vmcnt(0)" ::: "memory")
#define WAITL0() asm volatile("s_waitcnt lgkmcnt(0)" ::: "memory")

__device__ __forceinline__ u16 f2bf(float f) {
  u32 u = __float_as_uint(f);
  u32 r = (u + 0x7FFFu + ((u >> 16) & 1u)) >> 16;   // RNE
  return (u16)r;
}
__device__ __forceinline__ float bf2f(u16 h) {
  return __uint_as_float(((u32)h) << 16);
}
__device__ __forceinline__ u32 ordkey(float f) {
  u32 u = __float_as_uint(f);
  return (u & 0x80000000u) ? ~u : (u | 0x80000000u);
}
__device__ __forceinline__ void gload_lds16(const u16* g, u16* l) {
  __builtin_amdgcn_global_load_lds(
      (const __attribute__((address_space(1))) u32*)g,
      (__attribute__((address_space(3))) u32*)l, 16, 0, 0);
}
__device__ __forceinline__ float dot8(const H8& a, const H8& b, float c) {
#ifdef HAS_FDOT2
  c = __builtin_amdgcn_fdot2(a.a, b.a, c, false);
  c = __builtin_amdgcn_fdot2(a.b, b.b, c, false);
  c = __builtin_amdgcn_fdot2(a.c, b.c, c, false);
  c = __builtin_amdgcn_fdot2(a.d, b.d, c, false);
#else
  c += (float)a.a.x * (float)b.a.x + (float)a.a.y * (float)b.a.y;
  c += (float)a.b.x * (float)b.b.x + (float)a.b.y * (float)b.b.y;
  c += (float)a.c.x * (float)b.c.x + (float)a.c.y * (float)b.c.y;
  c += (float)a.d.x * (float)b.d.x + (float)a.d.y * (float)b.d.y;
#endif
  return c;
}
__device__ __forceinline__ int wrapNT(int t) { return t >= NT_ ? t - NT_ : t; }
__device__ __forceinline__ int acolf(int t) { t = wrapNT(t); return ((t >> 4) == 1 ? 1024 : 0) + (t & 15) * 64; }
__device__ __forceinline__ int bcolf(int t) { t = wrapNT(t); return ((t >> 4) == 2 ? 1024 : 0) + (t & 15) * 64; }

// ---------------- conversion kernels ----------------

__global__ void conv_split(const float* __restrict__ in, u16* __restrict__ out) {
  int r = blockIdx.x, t = threadIdx.x;
  float4 x = ((const float4*)(in + (size_t)r * D_))[t];
  U16x4 h, l;
  h.x = f2bf(x.x); l.x = f2bf(x.x - bf2f(h.x));
  h.y = f2bf(x.y); l.y = f2bf(x.y - bf2f(h.y));
  h.z = f2bf(x.z); l.z = f2bf(x.z - bf2f(h.z));
  h.w = f2bf(x.w); l.w = f2bf(x.w - bf2f(h.w));
  u16* o = out + (size_t)r * KS_ + t * 4;
  *(U16x4*)(o)      = h;
  *(U16x4*)(o + D_) = l;
}

__global__ void convProtos(const float* __restrict__ protos, const float* __restrict__ lin_w,
                           u16* __restrict__ p2,
                           float* __restrict__ psq, float* __restrict__ uu, float* __restrict__ vv) {
  int r = blockIdx.x, t = threadIdx.x;
  float4 x  = ((const float4*)(protos + (size_t)r * D_))[t];
  float4 w1 = ((const float4*)(lin_w))[t];
  float4 w2 = ((const float4*)(lin_w + D_))[t];
  U16x4 h, l;
  h.x = f2bf(x.x); l.x = f2bf(x.x - bf2f(h.x));
  h.y = f2bf(x.y); l.y = f2bf(x.y - bf2f(h.y));
  h.z = f2bf(x.z); l.z = f2bf(x.z - bf2f(h.z));
  h.w = f2bf(x.w); l.w = f2bf(x.w - bf2f(h.w));
  u16* o = p2 + (size_t)r * KS_ + t * 4;
  *(U16x4*)(o) = h; *(U16x4*)(o + D_) = l;

  float s1 = x.x*x.x + x.y*x.y + x.z*x.z + x.w*x.w;
  float s2 = x.x*w1.x + x.y*w1.y + x.z*w1.z + x.w*w1.w;
  float s3 = x.x*w2.x + x.y*w2.y + x.z*w2.z + x.w*w2.w;
  #pragma unroll
  for (int mk = 1; mk < 64; mk <<= 1) {
    s1 += __shfl_xor(s1, mk);
    s2 += __shfl_xor(s2, mk);
    s3 += __shfl_xor(s3, mk);
  }
  __shared__ float r1[4], r2[4], r3[4];
  if ((t & 63) == 0) { int w = t >> 6; r1[w] = s1; r2[w] = s2; r3[w] = s3; }
  __syncthreads();
  if (t == 0) {
    psq[r] = r1[0] + r1[1] + r1[2] + r1[3];
    uu[r]  = r2[0] + r2[1] + r2[2] + r2[3];
    vv[r]  = r3[0] + r3[1] + r3[2] + r3[3];
  }
}

__global__ void convWt(const float* __restrict__ W, u16* __restrict__ wt2) {
  __shared__ float tile[64][65];
  int bx = blockIdx.x, by = blockIdx.y;
  int t = threadIdx.x;
  int c4 = (t & 15) * 4, r0 = t >> 4;
  #pragma unroll
  for (int rr = 0; rr < 64; rr += 16) {
    int r = rr + r0;
    float4 x = *(const float4*)(W + (size_t)(bx * 64 + r) * D_ + by * 64 + c4);
    tile[r][c4 + 0] = x.x; tile[r][c4 + 1] = x.y; tile[r][c4 + 2] = x.z; tile[r][c4 + 3] = x.w;
  }
  __syncthreads();
  #pragma unroll
  for (int rr = 0; rr < 64; rr += 16) {
    int r = rr + r0;
    U16x4 h, l;
    float v0 = tile[c4 + 0][r], v1 = tile[c4 + 1][r], v2 = tile[c4 + 2][r], v3 = tile[c4 + 3][r];
    h.x = f2bf(v0); l.x = f2bf(v0 - bf2f(h.x));
    h.y = f2bf(v1); l.y = f2bf(v1 - bf2f(h.y));
    h.z = f2bf(v2); l.z = f2bf(v2 - bf2f(h.z));
    h.w = f2bf(v3); l.w = f2bf(v3 - bf2f(h.w));
    u16* o = wt2 + (size_t)(by * 64 + r) * KS_ + bx * 64 + c4;
    *(U16x4*)(o) = h; *(U16x4*)(o + D_) = l;
  }
}

// ---------------- 256x256 8-phase GEMM (T2+T3+T4+T5), BT layout ----------------
// C = A.B^T over logical K=3072 (3-phase split-bf16), M x 1024.
// MODE 1: fused argmin of psq[n]-2*c -> packed atomicMin.
// MODE 2: store fp16 leaky_relu(c + bias[n]) to Ch.
// LDS ring: A/B x kk-half x dbuf = 8 half-slots of 16KB (128KB dynamic).
// Swizzle st_16x32: elem (r,c) of a [256][32] slot at byte (r*64) ^ ((r>>3&1)<<5) +..
template<int MODE>
__global__ __launch_bounds__(512) void gemm256(
    const u16* __restrict__ A, const u16* __restrict__ Bm,
    u16* __restrict__ Ch,
    const float* __restrict__ psq, u64* __restrict__ packed,
    const float* __restrict__ bias)
{
  extern __shared__ u16 lds[];   // 65536 u16 = 128KB
  int bid = blockIdx.x;                       // 256 blocks
  int wg = ((bid & 7) << 5) + (bid >> 3);     // XCD swizzle (q=32)
  int tm = wg >> 2, tn = wg & 3;
  int m0 = tm << 8, n0 = tn << 8;

  int tid = threadIdx.x;
  int w = tid >> 6, lane = tid & 63;
  int wm = w >> 2, wn = w & 3;                // 2(M) x 4(N) waves; 128x64 each
  int lr = lane & 15, lg = lane >> 4;

  // LDS element offsets: A slot(kkh,buf) = (kkh*2+buf)*8192 ; B = +32768
  #define AOFF(kkh, buf) (((kkh) * 2 + (buf)) * 8192)
  #define BOFF(kkh, buf) (32768 + ((kkh) * 2 + (buf)) * 8192)

  // stage one half-slot: 256 rows x 32 cols bf16; 2 x global_load_lds per thread
  auto stage = [&](const u16* src, int row0, int colbase, int dstoff) {
    #pragma unroll
    for (int q = 0; q < 2; ++q) {
      int r = q * 128 + w * 16 + (lane >> 2);
      int c = ((lane & 3) * 8) ^ (((r >> 3) & 1) << 4);   // inverse-swizzled source
      gload_lds16(src + (size_t)(row0 + r) * KS_ + colbase + c,
                  &lds[dstoff + q * 4096 + w * 512]);
    }
  };

  // prologue: t0.kk0(A,B), t0.kk1(A,B), t1.kk0(A,B)  -> 12 loads; drain t0.kk0
  stage(A,  m0, acolf(0) +  0, AOFF(0, 0));
  stage(Bm, n0, bcolf(0) +  0, BOFF(0, 0));
  stage(A,  m0, acolf(0) + 32, AOFF(1, 0));
  stage(Bm, n0, bcolf(0) + 32, BOFF(1, 0));
  stage(A,  m0, acolf(1) +  0, AOFF(0, 1));
  stage(Bm, n0, bcolf(1) +  0, BOFF(0, 1));
  WAITV8();
  SBAR();

  f32x4 acc[8][4];
  #pragma unroll
  for (int i = 0; i < 8; ++i)
    #pragma unroll
    for (int j = 0; j < 4; ++j)
      acc[i][j] = (f32x4){0.f, 0.f, 0.f, 0.f};

  short8 bq[4];
  for (int t = 0; t < NT_; ++t) {
    int buf = t & 1;
    #pragma unroll
    for (int ph = 0; ph < 4; ++ph) {
      const int kkh = ph >> 1, mh = ph & 1;
      const u16* Asl = &lds[AOFF(kkh, buf)];
      const u16* Bsl = &lds[BOFF(kkh, buf)];
      short8 af[4];
      #pragma unroll
      for (int mi = 0; mi < 4; ++mi) {
        int r = wm * 128 + mh * 64 + mi * 16 + lr;
        af[mi] = *(const short8*)&Asl[r * 32 + ((lg * 8) ^ (((r >> 3) & 1) << 4))];
      }
      if (mh == 0) {
        #pragma unroll
        for (int nj = 0; nj < 4; ++nj) {
          int r = wn * 64 + nj * 16 + lr;
          bq[nj] = *(const short8*)&Bsl[r * 32 + ((lg * 8) ^ (((r >> 3) & 1) << 4))];
        }
      }
      // staggered staging: each target slot died >=1 barrier-pair ago
      if      (ph == 0) stage(A,  m0, acolf(t + 1) + 32, AOFF(1, (t + 1) & 1));
      else if (ph == 1) stage(Bm, n0, bcolf(t + 1) + 32, BOFF(1, (t + 1) & 1));
      else if (ph == 2) stage(A,  m0, acolf(t + 2) +  0, AOFF(0, buf));
      else              stage(Bm, n0, bcolf(t + 2) +  0, BOFF(0, buf));
      if (ph & 1) WAITV8();        // counted drain: oldest 4 = next-needed half-slots
      SBAR();
      WAITL0(); SFENCE();
      __builtin_amdgcn_s_setprio(1);
      #pragma unroll
      for (int mi = 0; mi < 4; ++mi)
        #pragma unroll
        for (int nj = 0; nj < 4; ++nj)
          acc[mh * 4 + mi][nj] =
            __builtin_amdgcn_mfma_f32_16x16x32_bf16(af[mi], bq[nj], acc[mh * 4 + mi][nj], 0, 0, 0);
      __builtin_amdgcn_s_setprio(0);
      SFENCE();
      SBAR();
    }
  }
  WAITV0();   // drain dummy prefetches before LDS dealloc / epilogue

  if (MODE == 1) {
    float pq[4];
    #pragma unroll
    for (int nj = 0; nj < 4; ++nj) pq[nj] = psq[n0 + wn * 64 + nj * 16 + lr];
    #pragma unroll
    for (int mi = 0; mi < 8; ++mi) {
      #pragma unroll
      for (int r = 0; r < 4; ++r) {
        float best = 1e30f; int bestn = 0x7fffffff;
        #pragma unroll
        for (int nj = 0; nj < 4; ++nj) {
          int n = n0 + wn * 64 + nj * 16 + lr;
          float d = pq[nj] - 2.0f * acc[mi][nj][r];
          if (d < best || (d == best && n < bestn)) { best = d; bestn = n; }
        }
        #pragma unroll
        for (int mk = 1; mk < 16; mk <<= 1) {
          float od = __shfl_xor(best, mk);
          int   on = __shfl_xor(bestn, mk);
          if (od < best || (od == best && on < bestn)) { best = od; bestn = on; }
        }
        if (lr == 0) {
          int m = m0 + wm * 128 + mi * 16 + lg * 4 + r;
          u64 key = ((u64)ordkey(best) << 32) | (u32)bestn;
          atomicMin(&packed[m], key);
        }
      }
    }
  } else {
    float bc[4];
    #pragma unroll
    for (int nj = 0; nj < 4; ++nj) bc[nj] = bias[n0 + wn * 64 + nj * 16 + lr];
    #pragma unroll
    for (int mi = 0; mi < 8; ++mi)
      #pragma unroll
      for (int nj = 0; nj < 4; ++nj)
        #pragma unroll
        for (int r = 0; r < 4; ++r) {
          int m = m0 + wm * 128 + mi * 16 + lg * 4 + r;
          int n = n0 + wn * 64 + nj * 16 + lr;
          float val = acc[mi][nj][r] + bc[nj];
          val = val >= 0.f ? val : 0.01f * val;
          half_t hv = (half_t)val;
          Ch[(size_t)m * P_ + n] = __builtin_bit_cast(u16, hv);
        }
  }
  #undef AOFF
  #undef BOFF
}

// ---------------- T = protos @ W, split-K x3 (m97 128^2 structure) ----------------
__global__ __launch_bounds__(256) void gemm_T_splitk(
    const u16* __restrict__ A, const u16* __restrict__ Bm, float* __restrict__ Cp)
{
  __shared__ u16 As[128 * 32];
  __shared__ u16 Bs[128 * 32];

  int bid = blockIdx.x;                  // 192
  int swz = (bid & 7) * 24 + (bid >> 3); // XCD swizzle (q=24)
  int kp = swz >> 6;                     // 0..2 K-phase
  int wg = swz & 63;
  int tm = wg >> 3, tn = wg & 7;
  int m0 = tm * 128, n0 = tn * 128;
  int abase = (kp == 1) ? 1024 : 0;
  int bbase = (kp == 2) ? 1024 : 0;

  int t = threadIdx.x;
  int w = t >> 6, lane = t & 63;
  int wr = w >> 1, wc = w & 1;
  int lr = lane & 15, lg = lane >> 4;

  const u16* src = (w < 2) ? A : Bm;
  int base_row = (w < 2) ? m0 : n0;
  int kbase = (w < 2) ? abase : bbase;
  int half = w & 1;
  int srow = base_row + half * 64 + (lane >> 2);
  int scol = (lane & 3) * 8;
  const u16* gsrc = src + (size_t)srow * KS_ + kbase + scol;
  u16* lbase = ((w < 2) ? As : Bs) + half * 2048;

  f32x4 acc[4][4];
  #pragma unroll
  for (int i = 0; i < 4; ++i)
    #pragma unroll
    for (int j = 0; j < 4; ++j)
      acc[i][j] = (f32x4){0.f, 0.f, 0.f, 0.f};

  for (int kt = 0; kt < 32; ++kt) {
    #pragma unroll
    for (int p = 0; p < 4; ++p)
      gload_lds16(gsrc + kt * 32 + (size_t)p * 16 * KS_, lbase + p * 512);
    __syncthreads();
    short8 af[4], bfr[4];
    #pragma unroll
    for (int i = 0; i < 4; ++i)
      af[i] = *(const short8*)&As[(wr * 64 + i * 16 + lr) * 32 + lg * 8];
    #pragma unroll
    for (int j = 0; j < 4; ++j)
      bfr[j] = *(const short8*)&Bs[(wc * 64 + j * 16 + lr) * 32 + lg * 8];
    #pragma unroll
    for (int i = 0; i < 4; ++i)
      #pragma unroll
      for (int j = 0; j < 4; ++j)
        acc[i][j] = __builtin_amdgcn_mfma_f32_16x16x32_bf16(af[i], bfr[j], acc[i][j], 0, 0, 0);
    __syncthreads();
  }

  float* Co = Cp + (size_t)kp * (P_ * D_);
  #pragma unroll
  for (int i = 0; i < 4; ++i)
    #pragma unroll
    for (int j = 0; j < 4; ++j)
      #pragma unroll
      for (int r = 0; r < 4; ++r) {
        int m = m0 + wr * 64 + i * 16 + lg * 4 + r;
        int n = n0 + wc * 64 + j * 16 + lr;
        Co[(size_t)m * D_ + n] = acc[i][j][r];
      }
}

// ---------------- mix: lam + adaptive mixup (sums 3 T-partials inline) ----------------
__global__ void mix_kernel(const u64* __restrict__ packed, const int* __restrict__ index,
                           const float* __restrict__ Tp, const float* __restrict__ protos,
                           const float* __restrict__ patient,
                           const float* __restrict__ uu, const float* __restrict__ vv,
                           const float* __restrict__ bilb, u16* __restrict__ mixed2)
{
  int b = blockIdx.x, t = threadIdx.x;
  int la = (int)(packed[b] & 0xffffffffULL);
  int ib = index[b];
  int lb = (int)(packed[ib] & 0xffffffffULL);

  float4 t0 = ((const float4*)(Tp + (size_t)la * D_))[t];
  float4 t1 = ((const float4*)(Tp + (size_t)(P_ * D_) + (size_t)la * D_))[t];
  float4 t2 = ((const float4*)(Tp + (size_t)(2 * P_ * D_) + (size_t)la * D_))[t];
  float4 pb = ((const float4*)(protos + (size_t)lb * D_))[t];
  float tax = t0.x + t1.x + t2.x, tay = t0.y + t1.y + t2.y;
  float taz = t0.z + t1.z + t2.z, taw = t0.w + t1.w + t2.w;
  float part = tax*pb.x + tay*pb.y + taz*pb.z + taw*pb.w;
  #pragma unroll
  for (int mk = 1; mk < 64; mk <<= 1) part += __shfl_xor(part, mk);
  __shared__ float ws4[4];
  __shared__ float lamsh;
  if ((t & 63) == 0) ws4[t >> 6] = part;
  __syncthreads();
  if (t == 0) {
    float dot = ws4[0] + ws4[1] + ws4[2] + ws4[3];
    float z = dot + bilb[0] + uu[la] + vv[lb];
    lamsh = 1.0f / (1.0f + expf(-z));
  }
  __syncthreads();
  float lam = lamsh, oml = 1.0f - lam;

  float4 xa = ((const float4*)(patient + (size_t)b  * D_))[t];
  float4 xb = ((const float4*)(patient + (size_t)ib * D_))[t];
  float m0v = lam * xa.x + oml * xb.x;
  float m1v = lam * xa.y + oml * xb.y;
  float m2v = lam * xa.z + oml * xb.z;
  float m3v = lam * xa.w + oml * xb.w;
  U16x4 h, l;
  h.x = f2bf(m0v); l.x = f2bf(m0v - bf2f(h.x));
  h.y = f2bf(m1v); l.y = f2bf(m1v - bf2f(h.y));
  h.z = f2bf(m2v); l.z = f2bf(m2v - bf2f(h.z));
  h.w = f2bf(m3v); l.w = f2bf(m3v - bf2f(h.w));
  u16* o = mixed2 + (size_t)b * KS_ + t * 4;
  *(U16x4*)(o) = h; *(U16x4*)(o + D_) = l;
}

// ---------------- cls: out = pl_fp16 @ cls_w^T + b (w staged fp16 in LDS) ----------------
__global__ __launch_bounds__(256) void cls_kernel(const u16* __restrict__ pl,
                                                  const float* __restrict__ w,
                                                  const float* __restrict__ bias,
                                                  float* __restrict__ out)
{
  __shared__ half_t wl[25 * 1032];
  int t = threadIdx.x;
  for (int i = t; i < 25 * 256; i += 256) {
    float4 v = ((const float4*)w)[i];
    int o = i >> 8;
    int col = (i & 255) * 4;
    H4 hh; hh.x = (half_t)v.x; hh.y = (half_t)v.y; hh.z = (half_t)v.z; hh.w = (half_t)v.w;
    *(H4*)&wl[o * 1032 + col] = hh;
  }
  __syncthreads();

  int row = blockIdx.x * 64 + (t >> 2);
  int osub = t & 3;
  const H8* prow = (const H8*)(pl + (size_t)row * P_);
  float acc[7] = {0.f, 0.f, 0.f, 0.f, 0.f, 0.f, 0.f};

  for (int kk = 0; kk < 128; ++kk) {
    H8 a = prow[kk];
    #pragma unroll
    for (int j = 0; j < 7; ++j) {
      int o = 4 * j + osub;
      if (o < 25) {
        H8 wv = *(const H8*)&wl[o * 1032 + kk * 8];
        acc[j] = dot8(a, wv, acc[j]);
      }
    }
  }
  #pragma unroll
  for (int j = 0; j < 7; ++j) {
    int o = 4 * j + osub;
    if (o < 25) out[(size_t)row * OUT_ + o] = acc[j] + bias[o];
  }
}

extern "C" void kernel_launch(void* const* d_in, const int* in_sizes, int n_in,
                              void* d_out, int out_size, void* d_ws, size_t ws_size,
                              hipStream_t stream)
{
  const float* patient = (const float*)d_in[0];
  const float* protos  = (const float*)d_in[1];
  const int*   index   = (const int*)d_in[2];
  const float* W       = (const float*)d_in[3];
  const float* bilb    = (const float*)d_in[4];
  const float* lin_w   = (const float*)d_in[5];
  const float* pfc_w   = (const float*)d_in[6];
  const float* pfc_b   = (const float*)d_in[7];
  const float* cls_w   = (const float*)d_in[8];
  const float* cls_b   = (const float*)d_in[9];
  float* out = (float*)d_out;

  char* ws = (char*)d_ws;
  size_t off = 0;
  auto carve = [&](size_t bytes) -> char* {
    char* p = ws + off; off += (bytes + 255) & ~(size_t)255; return p;
  };
  u16* buf2   = (u16*)carve((size_t)B_ * KS_ * 2);   // patient split, later mixed split
  u16* plh    = (u16*)carve((size_t)B_ * P_ * 2);    // fp16 leaky(proto_logits)
  u16* p2     = (u16*)carve((size_t)P_ * KS_ * 2);   // protos split
  u16* pfc2   = (u16*)carve((size_t)P_ * KS_ * 2);
  u16* wt2    = (u16*)carve((size_t)D_ * KS_ * 2);
  float* Tp   = (float*)carve((size_t)3 * P_ * D_ * 4);  // T split-K partials
  u64* packed = (u64*)carve((size_t)B_ * 8);
  float* psq  = (float*)carve(P_ * 4);
  float* uu   = (float*)carve(P_ * 4);
  float* vv   = (float*)carve(P_ * 4);

  hipMemsetAsync(packed, 0xFF, (size_t)B_ * 8, stream);

  convProtos<<<P_, 256, 0, stream>>>(protos, lin_w, p2, psq, uu, vv);
  convWt<<<dim3(16, 16), 256, 0, stream>>>(W, wt2);
  conv_split<<<P_, 256, 0, stream>>>(pfc_w, pfc2);
  conv_split<<<B_, 256, 0, stream>>>(patient, buf2);

  // T = protos @ W, split-K x3 partials
  gemm_T_splitk<<<192, 256, 0, stream>>>(p2, wt2, Tp);
  // distances + fused argmin (256^2 8-phase)
  gemm256<1><<<256, 512, 131072, stream>>>(buf2, p2, nullptr, psq, packed, nullptr);
  // lam + mixup (overwrites buf2 with mixed split; sums T partials inline)
  mix_kernel<<<B_, 256, 0, stream>>>(packed, index, Tp, protos, patient, uu, vv, bilb, buf2);
  // proto_logits with fused bias+leaky -> fp16 (256^2 8-phase)
  gemm256<2><<<256, 512, 131072, stream>>>(buf2, pfc2, plh, nullptr, nullptr, pfc_b);
  // final 25-wide projection
  cls_kernel<<<256, 256, 0, stream>>>(plh, cls_w, cls_b, out);
}